// Round 5
// baseline (139.159 us; speedup 1.0000x reference)
//
#include <hip/hip_runtime.h>

#define S_DIM 16
#define B_DIM 512
#define H_DIM 2048
#define EPS 1e-8f

typedef short bf16x8 __attribute__((ext_vector_type(8)));
typedef float f32x16 __attribute__((ext_vector_type(16)));

__device__ __forceinline__ unsigned short f2bf(float f) {
    union { float f; unsigned int u; } v; v.f = f;
    unsigned int u = v.u;
    unsigned int r = (u + 0x7fffu + ((u >> 16) & 1u)) >> 16;
    return (unsigned short)r;
}

__device__ __forceinline__ float dot4(const float4& a, const float4& b) {
    return a.x*b.x + a.y*b.y + a.z*b.z + a.w*b.w;
}

// ---------------- Kernel A: fused sims + weighted mean -> wrep, W->bf16 ----------------
// (R4, unchanged: at its ~94 MiB BW floor.) W loads issue first and convert
// under the E stream; OG shared via LDS; two barriers total.
__global__ __launch_bounds__(512, 4) void fused_kernel(
    const float* __restrict__ OG, const float* __restrict__ E,
    const float* __restrict__ W, unsigned short* __restrict__ wrep,
    unsigned short* __restrict__ Wb) {
    const int b = blockIdx.x;
    const int t = threadIdx.x;
    const int lane = t & 63;
    const int wave = t >> 6;

    __shared__ float4 buf[8][512];   // 64 KiB
    __shared__ float4 ogs[512];      // 8 KiB
    __shared__ float red[8];

    const float4* w4 = (const float4*)W;
    ushort4* wb4 = (ushort4*)Wb;
    const size_t wbase = (size_t)b * 2048 + t;

    float4 wv0 = w4[wbase];
    float4 wv1 = w4[wbase + 512];
    const float4* og4 = (const float4*)(OG + (size_t)b * H_DIM);
    float4 o = og4[t];

    const float4* e4a = (const float4*)(E + ((size_t)wave * B_DIM + b) * H_DIM);
    const float4* e4b = (const float4*)(E + ((size_t)(wave + 8) * B_DIM + b) * H_DIM);
    float4 ea[8], eb[8];
    #pragma unroll
    for (int i = 0; i < 8; ++i) {
        ea[i] = e4a[i * 64 + lane];
        eb[i] = e4b[i * 64 + lane];
    }
    float4 wv2 = w4[wbase + 1024];
    float4 wv3 = w4[wbase + 1536];

    ogs[t] = o;
    float p = dot4(o, o);
    #pragma unroll
    for (int m = 32; m >= 1; m >>= 1) p += __shfl_xor(p, m, 64);
    if (lane == 0) red[wave] = p;

    {
        ushort4 c0, c1;
        c0.x = f2bf(wv0.x); c0.y = f2bf(wv0.y); c0.z = f2bf(wv0.z); c0.w = f2bf(wv0.w);
        c1.x = f2bf(wv1.x); c1.y = f2bf(wv1.y); c1.z = f2bf(wv1.z); c1.w = f2bf(wv1.w);
        wb4[wbase] = c0;
        wb4[wbase + 512] = c1;
    }
    __syncthreads();

    float og2 = 0.f;
    #pragma unroll
    for (int w = 0; w < 8; ++w) og2 += red[w];
    const float onorm = sqrtf(og2);

    float da = 0.f, na = 0.f, db = 0.f, nb = 0.f;
    #pragma unroll
    for (int i = 0; i < 8; ++i) {
        float4 g = ogs[i * 64 + lane];
        da += dot4(ea[i], g); na += dot4(ea[i], ea[i]);
        db += dot4(eb[i], g); nb += dot4(eb[i], eb[i]);
    }
    #pragma unroll
    for (int m = 32; m >= 1; m >>= 1) {
        da += __shfl_xor(da, m, 64);
        na += __shfl_xor(na, m, 64);
        db += __shfl_xor(db, m, 64);
        nb += __shfl_xor(nb, m, 64);
    }
    const float sima = da / fmaxf(sqrtf(na) * onorm, EPS);
    const float simb = db / fmaxf(sqrtf(nb) * onorm, EPS);

    #pragma unroll
    for (int i = 0; i < 8; ++i) {
        float4 v;
        v.x = ea[i].x * sima + eb[i].x * simb;
        v.y = ea[i].y * sima + eb[i].y * simb;
        v.z = ea[i].z * sima + eb[i].z * simb;
        v.w = ea[i].w * sima + eb[i].w * simb;
        buf[wave][i * 64 + lane] = v;
    }
    {
        ushort4 c2, c3;
        c2.x = f2bf(wv2.x); c2.y = f2bf(wv2.y); c2.z = f2bf(wv2.z); c2.w = f2bf(wv2.w);
        c3.x = f2bf(wv3.x); c3.y = f2bf(wv3.y); c3.z = f2bf(wv3.z); c3.w = f2bf(wv3.w);
        wb4[wbase + 1024] = c2;
        wb4[wbase + 1536] = c3;
    }
    __syncthreads();

    float4 s = buf[0][t];
    #pragma unroll
    for (int w = 1; w < 8; ++w) {
        float4 v = buf[w][t];
        s.x += v.x; s.y += v.y; s.z += v.z; s.w += v.w;
    }
    const float sc = 1.f / (float)S_DIM;
    ushort4 ob;
    ob.x = f2bf(s.x * sc); ob.y = f2bf(s.y * sc);
    ob.z = f2bf(s.z * sc); ob.w = f2bf(s.w * sc);
    ((ushort4*)wrep)[(size_t)b * (H_DIM / 4) + t] = ob;
}

// ---------------- Kernel C: out = wrep @ Wb^T + b  (bf16 MFMA 32x32x16) ----------------
// LDS-traffic-minimal design: 64x64 tile, 4 waves EACH computing the full
// 64x64 (4 independent acc chains) over their OWN K-quarter (ks = wave id)
// -> every staged fragment is ds_read exactly ONCE (dup 1 vs 2). Staging via
// global_load_lds (16B, no ds_write instrs, no VGPR round trip): linear LDS
// dest + inverse-swizzled per-lane GLOBAL source (rule #21), reads use the
// same XOR (row&7)<<4 -> conflict-free ds_read_b128 (m214 pattern). One
// barrier per K-tile (m97 schedule: stage nxt, compute cur, barrier).
// Final cross-wave K-reduction through LDS. XCD n-partition: each XCD's 32
// blocks share A (2 MiB) + 4 B-panels (1 MiB) = 3 MiB, L2-resident.
__global__ __launch_bounds__(256) void gemm_kernel(
    const unsigned short* __restrict__ A, const unsigned short* __restrict__ Wb,
    const float* __restrict__ bias, float* __restrict__ out) {
    const int bid = blockIdx.x;
    const int xcd = bid & 7, j = bid >> 3;          // j = 0..31
    const int n0 = (xcd * 4 + (j & 3)) * 64;
    const int m0 = (j >> 2) * 64;

    __shared__ unsigned short As[2][64 * 64];       // 16 KiB, row stride 128 B
    __shared__ unsigned short Bs[2][64 * 64];       // 16 KiB
    __shared__ float red[4][16][256];               // 64 KiB K-partial exchange

    const int t = threadIdx.x;
    const int lane = t & 63;
    const int kh = t >> 6;                          // wave id == K-quarter

    // staging: chunk p covers rows p*32 + t/8, 16 B at column (t&7)*16.
    // LDS dest is LINEAR; the global SOURCE column is pre-(un)swizzled.
    const int srow0 = t >> 3;
    const int srow1 = srow0 + 32;
    const int colb = (t & 7) << 4;
    const int sc0 = colb ^ ((srow0 & 7) << 4);
    const int sc1 = colb ^ ((srow1 & 7) << 4);
    const unsigned short* apg0 = A  + (size_t)(m0 + srow0) * H_DIM + (sc0 >> 1);
    const unsigned short* apg1 = A  + (size_t)(m0 + srow1) * H_DIM + (sc1 >> 1);
    const unsigned short* bpg0 = Wb + (size_t)(n0 + srow0) * H_DIM + (sc0 >> 1);
    const unsigned short* bpg1 = Wb + (size_t)(n0 + srow1) * H_DIM + (sc1 >> 1);

    #define GLL(SRC, DST)                                                   \
        __builtin_amdgcn_global_load_lds(                                   \
            (const __attribute__((address_space(1))) unsigned int*)(const void*)(SRC), \
            (__attribute__((address_space(3))) unsigned int*)(void*)(DST),  \
            16, 0, 0)
    #define STAGE(BUF, KI)                                  \
        do {                                                \
            GLL(apg0 + (KI) * 64, &As[BUF][t * 8]);         \
            GLL(apg1 + (KI) * 64, &As[BUF][2048 + t * 8]);  \
            GLL(bpg0 + (KI) * 64, &Bs[BUF][t * 8]);         \
            GLL(bpg1 + (KI) * 64, &Bs[BUF][2048 + t * 8]);  \
        } while (0)

    // fragment read offsets (swizzled): wave kh reads k-slice kh*16..+16
    const int row = lane & 31;
    const int hi = lane >> 5;
    const int off0 = row * 64 + ((((kh * 32 + hi * 16)) ^ ((row & 7) << 4)) >> 1);

    f32x16 acc0 = {0.f,0.f,0.f,0.f,0.f,0.f,0.f,0.f,0.f,0.f,0.f,0.f,0.f,0.f,0.f,0.f};
    f32x16 acc1 = acc0, acc2 = acc0, acc3 = acc0;

    STAGE(0, 0);
    __syncthreads();

    for (int ki = 0; ki < 32; ++ki) {
        const int cur = ki & 1;
        if (ki + 1 < 32) STAGE(cur ^ 1, ki + 1);    // lands during compute
        bf16x8 a0 = *(const bf16x8*)&As[cur][off0];
        bf16x8 a1 = *(const bf16x8*)&As[cur][off0 + 2048];
        bf16x8 b0 = *(const bf16x8*)&Bs[cur][off0];
        bf16x8 b1 = *(const bf16x8*)&Bs[cur][off0 + 2048];
        acc0 = __builtin_amdgcn_mfma_f32_32x32x16_bf16(a0, b0, acc0, 0, 0, 0);
        acc1 = __builtin_amdgcn_mfma_f32_32x32x16_bf16(a0, b1, acc1, 0, 0, 0);
        acc2 = __builtin_amdgcn_mfma_f32_32x32x16_bf16(a1, b0, acc2, 0, 0, 0);
        acc3 = __builtin_amdgcn_mfma_f32_32x32x16_bf16(a1, b1, acc3, 0, 0, 0);
        __syncthreads();                            // drains gll + ds reads
    }
    #undef STAGE
    #undef GLL

    // dump this wave's K-partial: slot = chain*4 + r4, 16 B/lane, conflict-free
    #define DUMP(C, ACC)                                                     \
        { _Pragma("unroll")                                                  \
          for (int r4 = 0; r4 < 4; ++r4) {                                   \
              float4 v = {(ACC)[r4*4], (ACC)[r4*4+1], (ACC)[r4*4+2], (ACC)[r4*4+3]}; \
              *(float4*)&red[kh][(C)*4 + r4][lane << 2] = v;                 \
          } }
    DUMP(0, acc0); DUMP(1, acc1); DUMP(2, acc2); DUMP(3, acc3);
    #undef DUMP
    __syncthreads();

    // wave kh merges the 4 K-partials of chain kh (qm=kh>>1, qn=kh&1)
    const int qm = kh >> 1, qn = kh & 1;
    const int col = n0 + qn * 32 + row;
    const float bias0 = bias[col];
    #pragma unroll
    for (int i = 0; i < 4; ++i) {
        const int s = kh * 4 + i;
        float4 v0 = *(float4*)&red[0][s][lane << 2];
        float4 v1 = *(float4*)&red[1][s][lane << 2];
        float4 v2 = *(float4*)&red[2][s][lane << 2];
        float4 v3 = *(float4*)&red[3][s][lane << 2];
        float4 v;
        v.x = v0.x + v1.x + v2.x + v3.x;
        v.y = v0.y + v1.y + v2.y + v3.y;
        v.z = v0.z + v1.z + v2.z + v3.z;
        v.w = v0.w + v1.w + v2.w + v3.w;
        // D mapping (32x32): col = lane&31, row = (r&3) + 8*(r>>2) + 4*hi
        const float vv[4] = {v.x, v.y, v.z, v.w};
        #pragma unroll
        for (int rr = 0; rr < 4; ++rr) {
            const int mr = rr + 8 * i + 4 * hi;
            out[(size_t)(m0 + qm * 32 + mr) * H_DIM + col] = vv[rr] + bias0;
        }
    }
}

extern "C" void kernel_launch(void* const* d_in, const int* in_sizes, int n_in,
                              void* d_out, int out_size, void* d_ws, size_t ws_size,
                              hipStream_t stream) {
    const float* OG   = (const float*)d_in[0];
    const float* E    = (const float*)d_in[1];
    const float* W    = (const float*)d_in[2];
    const float* bias = (const float*)d_in[3];
    float* out = (float*)d_out;

    unsigned short* wrep = (unsigned short*)d_ws;                 // 2 MiB bf16
    unsigned short* Wb   = wrep + (size_t)B_DIM * H_DIM;          // 8 MiB bf16

    fused_kernel<<<B_DIM, 512, 0, stream>>>(OG, E, W, wrep, Wb);
    gemm_kernel<<<256, 256, 0, stream>>>(wrep, Wb, bias, out);
}

// Round 6
// 137.205 us; speedup vs baseline: 1.0142x; 1.0142x over previous
//
#include <hip/hip_runtime.h>

#define S_DIM 16
#define B_DIM 512
#define H_DIM 2048
#define EPS 1e-8f

typedef short bf16x8 __attribute__((ext_vector_type(8)));
typedef float f32x16 __attribute__((ext_vector_type(16)));

__device__ __forceinline__ unsigned short f2bf(float f) {
    union { float f; unsigned int u; } v; v.f = f;
    unsigned int u = v.u;
    unsigned int r = (u + 0x7fffu + ((u >> 16) & 1u)) >> 16;
    return (unsigned short)r;
}

__device__ __forceinline__ uint4 pack8(const float4 a, const float4 b) {
    union { unsigned short u[8]; uint4 v; } r;
    r.u[0] = f2bf(a.x); r.u[1] = f2bf(a.y); r.u[2] = f2bf(a.z); r.u[3] = f2bf(a.w);
    r.u[4] = f2bf(b.x); r.u[5] = f2bf(b.y); r.u[6] = f2bf(b.z); r.u[7] = f2bf(b.w);
    return r.v;
}

__device__ __forceinline__ float dot4(const float4& a, const float4& b) {
    return a.x*b.x + a.y*b.y + a.z*b.z + a.w*b.w;
}

// ---------------- Kernel A: fused sims + weighted mean -> wrep ----------------
// R4 structure minus ALL W handling (W now consumed fp32 directly by the GEMM):
// reads E (64 MiB) + OG (4 MiB), writes wrep (2 MiB) -> ~11 us BW floor.
// Wave w owns E rows s=w, s=w+8; OG shared via LDS; two barriers.
__global__ __launch_bounds__(512, 4) void fused_kernel(
    const float* __restrict__ OG, const float* __restrict__ E,
    unsigned short* __restrict__ wrep) {
    const int b = blockIdx.x;
    const int t = threadIdx.x;
    const int lane = t & 63;
    const int wave = t >> 6;

    __shared__ float4 buf[8][512];   // 64 KiB
    __shared__ float4 ogs[512];      // 8 KiB
    __shared__ float red[8];

    const float4* og4 = (const float4*)(OG + (size_t)b * H_DIM);
    float4 o = og4[t];

    const float4* e4a = (const float4*)(E + ((size_t)wave * B_DIM + b) * H_DIM);
    const float4* e4b = (const float4*)(E + ((size_t)(wave + 8) * B_DIM + b) * H_DIM);
    float4 ea[8], eb[8];
    #pragma unroll
    for (int i = 0; i < 8; ++i) {
        ea[i] = e4a[i * 64 + lane];
        eb[i] = e4b[i * 64 + lane];
    }

    ogs[t] = o;
    float p = dot4(o, o);
    #pragma unroll
    for (int m = 32; m >= 1; m >>= 1) p += __shfl_xor(p, m, 64);
    if (lane == 0) red[wave] = p;
    __syncthreads();

    float og2 = 0.f;
    #pragma unroll
    for (int w = 0; w < 8; ++w) og2 += red[w];
    const float onorm = sqrtf(og2);

    float da = 0.f, na = 0.f, db = 0.f, nb = 0.f;
    #pragma unroll
    for (int i = 0; i < 8; ++i) {
        float4 g = ogs[i * 64 + lane];
        da += dot4(ea[i], g); na += dot4(ea[i], ea[i]);
        db += dot4(eb[i], g); nb += dot4(eb[i], eb[i]);
    }
    #pragma unroll
    for (int m = 32; m >= 1; m >>= 1) {
        da += __shfl_xor(da, m, 64);
        na += __shfl_xor(na, m, 64);
        db += __shfl_xor(db, m, 64);
        nb += __shfl_xor(nb, m, 64);
    }
    const float sima = da / fmaxf(sqrtf(na) * onorm, EPS);
    const float simb = db / fmaxf(sqrtf(nb) * onorm, EPS);

    #pragma unroll
    for (int i = 0; i < 8; ++i) {
        float4 v;
        v.x = ea[i].x * sima + eb[i].x * simb;
        v.y = ea[i].y * sima + eb[i].y * simb;
        v.z = ea[i].z * sima + eb[i].z * simb;
        v.w = ea[i].w * sima + eb[i].w * simb;
        buf[wave][i * 64 + lane] = v;
    }
    __syncthreads();

    float4 s = buf[0][t];
    #pragma unroll
    for (int w = 1; w < 8; ++w) {
        float4 v = buf[w][t];
        s.x += v.x; s.y += v.y; s.z += v.z; s.w += v.w;
    }
    const float sc = 1.f / (float)S_DIM;
    ushort4 ob;
    ob.x = f2bf(s.x * sc); ob.y = f2bf(s.y * sc);
    ob.z = f2bf(s.z * sc); ob.w = f2bf(s.w * sc);
    ((ushort4*)wrep)[(size_t)b * (H_DIM / 4) + t] = ob;
}

// ---------------- Kernel C: out = wrep @ bf16(W)^T + b  (MFMA 32x32x16) ----------------
// R4's proven 2-deep register pipeline (issue T(k+2), compute T(k), write
// T(k+1); one barrier per sub-iter) with two fixes:
//  * LDS row stride = 64 shorts (128 B, NO pad) + XOR byte^=(row&7)<<4 on
//    BOTH write and read -- the m201/m214-verified conflict-free combo.
//    (R4's pad-72+XOR collapsed to an 8-way read conflict: with stride
//    144 B the row term 9r mod 8 interferes with the XOR.)
//  * B staged DIRECTLY from W fp32, converted in-register via the same f2bf
//    (bit-identical Wb values -> identical numerics), killing the Wb
//    round-trip in kernel A. XCD n-partitioned: per XCD W-panel 2 MiB fp32
//    + wrep 2 MiB bf16 stay L2-resident.
__global__ __launch_bounds__(256) void gemm_kernel(
    const unsigned short* __restrict__ A, const float* __restrict__ W,
    const float* __restrict__ bias, float* __restrict__ out) {
    const int bid = blockIdx.x;
    const int xcd = bid & 7, j = bid >> 3;
    const int n0 = (xcd * 4 + (j & 3)) * 64;   // 32 n-tiles, 4 per XCD
    const int m0 = (j >> 2) * 64;              // 8 m-tiles

    __shared__ unsigned short As[2][64 * 64];  // 8 KiB each, stride 128 B
    __shared__ unsigned short Bs[2][64 * 64];

    const int t = threadIdx.x;
    const int lane = t & 63;
    const int wave = t >> 6;
    const int wm = (wave & 1) * 32;
    const int wn = (wave >> 1) * 32;

    const int lr = t >> 2, lq = t & 3;   // staging: 4 thr/row, 16 elems each
    const unsigned short* ap = A + (size_t)(m0 + lr) * H_DIM + lq * 16;
    const float*          wp = W + (size_t)(n0 + lr) * H_DIM + lq * 16;

    // swizzled write offsets (short units): byte = lq*32 (+16) XOR (lr&7)<<4
    const int swz = (lr & 7) << 4;
    const int w0 = lr * 64 + (((lq * 32) ^ swz) >> 1);
    const int w1 = lr * 64 + (((lq * 32 + 16) ^ swz) >> 1);

    f32x16 acc0 = {0.f,0.f,0.f,0.f,0.f,0.f,0.f,0.f,
                   0.f,0.f,0.f,0.f,0.f,0.f,0.f,0.f};
    f32x16 acc1 = acc0;

    const int row = lane & 31;
    const int hi = lane >> 5;
    const int rswz = (row & 7) << 4;
    int roffA[4], roffB[4];
    #pragma unroll
    for (int ks = 0; ks < 4; ++ks) {
        const int x = ((ks * 32 + hi * 16) ^ rswz) >> 1;
        roffA[ks] = (wm + row) * 64 + x;
        roffB[ks] = (wn + row) * 64 + x;
    }

    // prologue: T0 -> r-set, T1 -> s-set, write T0 to buf0
    uint4  ra0 = *(const uint4*)(ap);
    uint4  ra1 = *(const uint4*)(ap + 8);
    float4 rf0 = *(const float4*)(wp);
    float4 rf1 = *(const float4*)(wp + 4);
    float4 rf2 = *(const float4*)(wp + 8);
    float4 rf3 = *(const float4*)(wp + 12);
    uint4  sa0 = *(const uint4*)(ap + 64);
    uint4  sa1 = *(const uint4*)(ap + 72);
    float4 sf0 = *(const float4*)(wp + 64);
    float4 sf1 = *(const float4*)(wp + 68);
    float4 sf2 = *(const float4*)(wp + 72);
    float4 sf3 = *(const float4*)(wp + 76);
    *(uint4*)&As[0][w0] = ra0;
    *(uint4*)&As[0][w1] = ra1;
    *(uint4*)&Bs[0][w0] = pack8(rf0, rf1);
    *(uint4*)&Bs[0][w1] = pack8(rf2, rf3);
    __syncthreads();

    #define MFMA_TILE(BUF)                                                        \
    {                                                                             \
        _Pragma("unroll")                                                         \
        for (int ks = 0; ks < 2; ++ks) {                                          \
            bf16x8 afA = *(const bf16x8*)&As[BUF][roffA[ks]];                     \
            bf16x8 bfA = *(const bf16x8*)&Bs[BUF][roffB[ks]];                     \
            acc0 = __builtin_amdgcn_mfma_f32_32x32x16_bf16(afA, bfA, acc0, 0,0,0);\
            bf16x8 afB = *(const bf16x8*)&As[BUF][roffA[ks + 2]];                 \
            bf16x8 bfB = *(const bf16x8*)&Bs[BUF][roffB[ks + 2]];                 \
            acc1 = __builtin_amdgcn_mfma_f32_32x32x16_bf16(afB, bfB, acc1, 0,0,0);\
        }                                                                         \
    }

    for (int ki = 0; ki < 32; ki += 2) {
        if (ki + 2 < 32) {  // issue T_{ki+2} into freed r-set
            ra0 = *(const uint4*)(ap + (ki + 2) * 64);
            ra1 = *(const uint4*)(ap + (ki + 2) * 64 + 8);
            rf0 = *(const float4*)(wp + (ki + 2) * 64);
            rf1 = *(const float4*)(wp + (ki + 2) * 64 + 4);
            rf2 = *(const float4*)(wp + (ki + 2) * 64 + 8);
            rf3 = *(const float4*)(wp + (ki + 2) * 64 + 12);
        }
        MFMA_TILE(0);
        *(uint4*)&As[1][w0] = sa0;   // T_{ki+1}
        *(uint4*)&As[1][w1] = sa1;
        *(uint4*)&Bs[1][w0] = pack8(sf0, sf1);
        *(uint4*)&Bs[1][w1] = pack8(sf2, sf3);
        __syncthreads();
        if (ki + 3 < 32) {  // issue T_{ki+3} into freed s-set
            sa0 = *(const uint4*)(ap + (ki + 3) * 64);
            sa1 = *(const uint4*)(ap + (ki + 3) * 64 + 8);
            sf0 = *(const float4*)(wp + (ki + 3) * 64);
            sf1 = *(const float4*)(wp + (ki + 3) * 64 + 4);
            sf2 = *(const float4*)(wp + (ki + 3) * 64 + 8);
            sf3 = *(const float4*)(wp + (ki + 3) * 64 + 12);
        }
        MFMA_TILE(1);
        if (ki + 2 < 32) {
            *(uint4*)&As[0][w0] = ra0;   // T_{ki+2}
            *(uint4*)&As[0][w1] = ra1;
            *(uint4*)&Bs[0][w0] = pack8(rf0, rf1);
            *(uint4*)&Bs[0][w1] = pack8(rf2, rf3);
            __syncthreads();
        }
    }
    #undef MFMA_TILE

    // D mapping (32x32, m74/m101): col = lane&31 (N), row = (r&3)+8*(r>>2)+4*hi (M)
    const int col = lane & 31;
    const float bias0 = bias[n0 + wn + col];
    #pragma unroll
    for (int r = 0; r < 16; ++r) {
        const int mr = (r & 3) + 8 * (r >> 2) + 4 * hi;
        out[(size_t)(m0 + wm + mr) * H_DIM + n0 + wn + col] = acc0[r] + acc1[r] + bias0;
    }
}

extern "C" void kernel_launch(void* const* d_in, const int* in_sizes, int n_in,
                              void* d_out, int out_size, void* d_ws, size_t ws_size,
                              hipStream_t stream) {
    const float* OG   = (const float*)d_in[0];
    const float* E    = (const float*)d_in[1];
    const float* W    = (const float*)d_in[2];
    const float* bias = (const float*)d_in[3];
    float* out = (float*)d_out;

    unsigned short* wrep = (unsigned short*)d_ws;   // 2 MiB bf16

    fused_kernel<<<B_DIM, 512, 0, stream>>>(OG, E, wrep);
    gemm_kernel<<<256, 256, 0, stream>>>(wrep, W, bias, out);
}

// Round 7
// 120.692 us; speedup vs baseline: 1.1530x; 1.1368x over previous
//
#include <hip/hip_runtime.h>

#define S_DIM 16
#define B_DIM 512
#define H_DIM 2048
#define EPS 1e-8f

typedef short bf16x8 __attribute__((ext_vector_type(8)));
typedef float f32x16 __attribute__((ext_vector_type(16)));

__device__ __forceinline__ unsigned short f2bf(float f) {
    union { float f; unsigned int u; } v; v.f = f;
    unsigned int u = v.u;
    unsigned int r = (u + 0x7fffu + ((u >> 16) & 1u)) >> 16;
    return (unsigned short)r;
}

__device__ __forceinline__ float dot4(const float4& a, const float4& b) {
    return a.x*b.x + a.y*b.y + a.z*b.z + a.w*b.w;
}

// ---------------- Kernel A: fused sims + weighted mean -> wrep, W->bf16 ----------------
// (R4 verbatim -- measured in the 124.8 us config.) W loads issue first and
// convert under the E stream (overlap is free in this BW-bound kernel); OG
// shared via LDS; two barriers total.
__global__ __launch_bounds__(512, 4) void fused_kernel(
    const float* __restrict__ OG, const float* __restrict__ E,
    const float* __restrict__ W, unsigned short* __restrict__ wrep,
    unsigned short* __restrict__ Wb) {
    const int b = blockIdx.x;
    const int t = threadIdx.x;
    const int lane = t & 63;
    const int wave = t >> 6;

    __shared__ float4 buf[8][512];   // 64 KiB
    __shared__ float4 ogs[512];      // 8 KiB
    __shared__ float red[8];

    const float4* w4 = (const float4*)W;
    ushort4* wb4 = (ushort4*)Wb;
    const size_t wbase = (size_t)b * 2048 + t;

    float4 wv0 = w4[wbase];
    float4 wv1 = w4[wbase + 512];
    const float4* og4 = (const float4*)(OG + (size_t)b * H_DIM);
    float4 o = og4[t];

    const float4* e4a = (const float4*)(E + ((size_t)wave * B_DIM + b) * H_DIM);
    const float4* e4b = (const float4*)(E + ((size_t)(wave + 8) * B_DIM + b) * H_DIM);
    float4 ea[8], eb[8];
    #pragma unroll
    for (int i = 0; i < 8; ++i) {
        ea[i] = e4a[i * 64 + lane];
        eb[i] = e4b[i * 64 + lane];
    }
    float4 wv2 = w4[wbase + 1024];
    float4 wv3 = w4[wbase + 1536];

    ogs[t] = o;
    float p = dot4(o, o);
    #pragma unroll
    for (int m = 32; m >= 1; m >>= 1) p += __shfl_xor(p, m, 64);
    if (lane == 0) red[wave] = p;

    {
        ushort4 c0, c1;
        c0.x = f2bf(wv0.x); c0.y = f2bf(wv0.y); c0.z = f2bf(wv0.z); c0.w = f2bf(wv0.w);
        c1.x = f2bf(wv1.x); c1.y = f2bf(wv1.y); c1.z = f2bf(wv1.z); c1.w = f2bf(wv1.w);
        wb4[wbase] = c0;
        wb4[wbase + 512] = c1;
    }
    __syncthreads();

    float og2 = 0.f;
    #pragma unroll
    for (int w = 0; w < 8; ++w) og2 += red[w];
    const float onorm = sqrtf(og2);

    float da = 0.f, na = 0.f, db = 0.f, nb = 0.f;
    #pragma unroll
    for (int i = 0; i < 8; ++i) {
        float4 g = ogs[i * 64 + lane];
        da += dot4(ea[i], g); na += dot4(ea[i], ea[i]);
        db += dot4(eb[i], g); nb += dot4(eb[i], eb[i]);
    }
    #pragma unroll
    for (int m = 32; m >= 1; m >>= 1) {
        da += __shfl_xor(da, m, 64);
        na += __shfl_xor(na, m, 64);
        db += __shfl_xor(db, m, 64);
        nb += __shfl_xor(nb, m, 64);
    }
    const float sima = da / fmaxf(sqrtf(na) * onorm, EPS);
    const float simb = db / fmaxf(sqrtf(nb) * onorm, EPS);

    #pragma unroll
    for (int i = 0; i < 8; ++i) {
        float4 v;
        v.x = ea[i].x * sima + eb[i].x * simb;
        v.y = ea[i].y * sima + eb[i].y * simb;
        v.z = ea[i].z * sima + eb[i].z * simb;
        v.w = ea[i].w * sima + eb[i].w * simb;
        buf[wave][i * 64 + lane] = v;
    }
    {
        ushort4 c2, c3;
        c2.x = f2bf(wv2.x); c2.y = f2bf(wv2.y); c2.z = f2bf(wv2.z); c2.w = f2bf(wv2.w);
        c3.x = f2bf(wv3.x); c3.y = f2bf(wv3.y); c3.z = f2bf(wv3.z); c3.w = f2bf(wv3.w);
        wb4[wbase + 1024] = c2;
        wb4[wbase + 1536] = c3;
    }
    __syncthreads();

    float4 s = buf[0][t];
    #pragma unroll
    for (int w = 1; w < 8; ++w) {
        float4 v = buf[w][t];
        s.x += v.x; s.y += v.y; s.z += v.z; s.w += v.w;
    }
    const float sc = 1.f / (float)S_DIM;
    ushort4 ob;
    ob.x = f2bf(s.x * sc); ob.y = f2bf(s.y * sc);
    ob.z = f2bf(s.z * sc); ob.w = f2bf(s.w * sc);
    ((ushort4*)wrep)[(size_t)b * (H_DIM / 4) + t] = ob;
}

// ---------------- Kernel C: out = wrep @ Wb^T + b  (bf16 MFMA 32x32x16) ----------------
// R4's 2-deep register pipeline (issue T(k+2), compute T(k), write T(k+1);
// one barrier per sub-iter), staging Wb bf16 (NO in-GEMM conversion -- R6
// showed that costs ~100 serial VALU on the pre-barrier critical path).
// Two isolated fixes vs R4:
//  * LDS row stride 64 shorts (128 B, no pad) + XOR byte^=(row&7)<<4 on BOTH
//    write and read: granule = cg^row, bijective -> conflict-free ds_read_b128.
//    (R4's pad-72+XOR degenerated to ~8-way: granule (9r+cg^r) mod 8.)
//  * n-partitioned XCD map: per-XCD Wb panel (1 MiB) + wrep (2 MiB) < 4 MiB L2.
__global__ __launch_bounds__(256) void gemm_kernel(
    const unsigned short* __restrict__ A, const unsigned short* __restrict__ Wb,
    const float* __restrict__ bias, float* __restrict__ out) {
    const int bid = blockIdx.x;
    const int xcd = bid & 7, j = bid >> 3;
    const int n0 = (xcd * 4 + (j & 3)) * 64;   // 32 n-tiles, 4 per XCD
    const int m0 = (j >> 2) * 64;              // 8 m-tiles

    __shared__ unsigned short As[2][64 * 64];  // 8 KiB each, stride 128 B
    __shared__ unsigned short Bs[2][64 * 64];

    const int t = threadIdx.x;
    const int lane = t & 63;
    const int wave = t >> 6;
    const int wm = (wave & 1) * 32;
    const int wn = (wave >> 1) * 32;

    const int lr = t >> 2, lq = t & 3;   // staging: 4 thr/row, 32 shorts each
    const unsigned short* ap = A  + (size_t)(m0 + lr) * H_DIM + lq * 16;
    const unsigned short* bp = Wb + (size_t)(n0 + lr) * H_DIM + lq * 16;

    // swizzled write offsets (short units): byte = lq*32 (+16) XOR (lr&7)<<4
    const int swz = (lr & 7) << 4;
    const int w0 = lr * 64 + (((lq * 32) ^ swz) >> 1);
    const int w1 = lr * 64 + (((lq * 32 + 16) ^ swz) >> 1);

    f32x16 acc0 = {0.f,0.f,0.f,0.f,0.f,0.f,0.f,0.f,
                   0.f,0.f,0.f,0.f,0.f,0.f,0.f,0.f};
    f32x16 acc1 = acc0;

    const int row = lane & 31;
    const int hi = lane >> 5;
    const int rswz = (row & 7) << 4;
    int roffA[4], roffB[4];
    #pragma unroll
    for (int ks = 0; ks < 4; ++ks) {
        const int x = ((ks * 32 + hi * 16) ^ rswz) >> 1;
        roffA[ks] = (wm + row) * 64 + x;
        roffB[ks] = (wn + row) * 64 + x;
    }

    // prologue: T0 -> r-set, T1 -> s-set, write T0 to buf0
    uint4 ra0 = *(const uint4*)(ap);
    uint4 ra1 = *(const uint4*)(ap + 8);
    uint4 rb0 = *(const uint4*)(bp);
    uint4 rb1 = *(const uint4*)(bp + 8);
    uint4 sa0 = *(const uint4*)(ap + 64);
    uint4 sa1 = *(const uint4*)(ap + 72);
    uint4 sb0 = *(const uint4*)(bp + 64);
    uint4 sb1 = *(const uint4*)(bp + 72);
    *(uint4*)&As[0][w0] = ra0;
    *(uint4*)&As[0][w1] = ra1;
    *(uint4*)&Bs[0][w0] = rb0;
    *(uint4*)&Bs[0][w1] = rb1;
    __syncthreads();

    #define MFMA_TILE(BUF)                                                        \
    {                                                                             \
        _Pragma("unroll")                                                         \
        for (int ks = 0; ks < 2; ++ks) {                                          \
            bf16x8 afA = *(const bf16x8*)&As[BUF][roffA[ks]];                     \
            bf16x8 bfA = *(const bf16x8*)&Bs[BUF][roffB[ks]];                     \
            acc0 = __builtin_amdgcn_mfma_f32_32x32x16_bf16(afA, bfA, acc0, 0,0,0);\
            bf16x8 afB = *(const bf16x8*)&As[BUF][roffA[ks + 2]];                 \
            bf16x8 bfB = *(const bf16x8*)&Bs[BUF][roffB[ks + 2]];                 \
            acc1 = __builtin_amdgcn_mfma_f32_32x32x16_bf16(afB, bfB, acc1, 0,0,0);\
        }                                                                         \
    }

    for (int ki = 0; ki < 32; ki += 2) {
        if (ki + 2 < 32) {  // issue T_{ki+2} into freed r-set
            ra0 = *(const uint4*)(ap + (ki + 2) * 64);
            ra1 = *(const uint4*)(ap + (ki + 2) * 64 + 8);
            rb0 = *(const uint4*)(bp + (ki + 2) * 64);
            rb1 = *(const uint4*)(bp + (ki + 2) * 64 + 8);
        }
        MFMA_TILE(0);
        *(uint4*)&As[1][w0] = sa0;   // T_{ki+1}
        *(uint4*)&As[1][w1] = sa1;
        *(uint4*)&Bs[1][w0] = sb0;
        *(uint4*)&Bs[1][w1] = sb1;
        __syncthreads();
        if (ki + 3 < 32) {  // issue T_{ki+3} into freed s-set
            sa0 = *(const uint4*)(ap + (ki + 3) * 64);
            sa1 = *(const uint4*)(ap + (ki + 3) * 64 + 8);
            sb0 = *(const uint4*)(bp + (ki + 3) * 64);
            sb1 = *(const uint4*)(bp + (ki + 3) * 64 + 8);
        }
        MFMA_TILE(1);
        if (ki + 2 < 32) {
            *(uint4*)&As[0][w0] = ra0;   // T_{ki+2}
            *(uint4*)&As[0][w1] = ra1;
            *(uint4*)&Bs[0][w0] = rb0;
            *(uint4*)&Bs[0][w1] = rb1;
            __syncthreads();
        }
    }
    #undef MFMA_TILE

    // D mapping (32x32, m74/m101): col = lane&31 (N), row = (r&3)+8*(r>>2)+4*hi (M)
    const int col = lane & 31;
    const float bias0 = bias[n0 + wn + col];
    #pragma unroll
    for (int r = 0; r < 16; ++r) {
        const int mr = (r & 3) + 8 * (r >> 2) + 4 * hi;
        out[(size_t)(m0 + wm + mr) * H_DIM + n0 + wn + col] = acc0[r] + acc1[r] + bias0;
    }
}

extern "C" void kernel_launch(void* const* d_in, const int* in_sizes, int n_in,
                              void* d_out, int out_size, void* d_ws, size_t ws_size,
                              hipStream_t stream) {
    const float* OG   = (const float*)d_in[0];
    const float* E    = (const float*)d_in[1];
    const float* W    = (const float*)d_in[2];
    const float* bias = (const float*)d_in[3];
    float* out = (float*)d_out;

    unsigned short* wrep = (unsigned short*)d_ws;                 // 2 MiB bf16
    unsigned short* Wb   = wrep + (size_t)B_DIM * H_DIM;          // 8 MiB bf16

    fused_kernel<<<B_DIM, 512, 0, stream>>>(OG, E, W, wrep, Wb);
    gemm_kernel<<<256, 256, 0, stream>>>(wrep, Wb, bias, out);
}

// Round 9
// 120.064 us; speedup vs baseline: 1.1590x; 1.0052x over previous
//
#include <hip/hip_runtime.h>

#define S_DIM 16
#define B_DIM 512
#define H_DIM 2048
#define EPS 1e-8f

typedef short bf16x8 __attribute__((ext_vector_type(8)));
typedef float f32x16 __attribute__((ext_vector_type(16)));

__device__ __forceinline__ unsigned short f2bf(float f) {
    union { float f; unsigned int u; } v; v.f = f;
    unsigned int u = v.u;
    unsigned int r = (u + 0x7fffu + ((u >> 16) & 1u)) >> 16;
    return (unsigned short)r;
}

__device__ __forceinline__ float dot4(const float4& a, const float4& b) {
    return a.x*b.x + a.y*b.y + a.z*b.z + a.w*b.w;
}

// ---------------- Kernel A: fused sims + weighted mean -> wrep, W->bf16 ----------------
// (R7 verbatim -- measured in the 120.7 us config, at its ~94 MiB BW floor.)
__global__ __launch_bounds__(512, 4) void fused_kernel(
    const float* __restrict__ OG, const float* __restrict__ E,
    const float* __restrict__ W, unsigned short* __restrict__ wrep,
    unsigned short* __restrict__ Wb) {
    const int b = blockIdx.x;
    const int t = threadIdx.x;
    const int lane = t & 63;
    const int wave = t >> 6;

    __shared__ float4 buf[8][512];   // 64 KiB
    __shared__ float4 ogs[512];      // 8 KiB
    __shared__ float red[8];

    const float4* w4 = (const float4*)W;
    ushort4* wb4 = (ushort4*)Wb;
    const size_t wbase = (size_t)b * 2048 + t;

    float4 wv0 = w4[wbase];
    float4 wv1 = w4[wbase + 512];
    const float4* og4 = (const float4*)(OG + (size_t)b * H_DIM);
    float4 o = og4[t];

    const float4* e4a = (const float4*)(E + ((size_t)wave * B_DIM + b) * H_DIM);
    const float4* e4b = (const float4*)(E + ((size_t)(wave + 8) * B_DIM + b) * H_DIM);
    float4 ea[8], eb[8];
    #pragma unroll
    for (int i = 0; i < 8; ++i) {
        ea[i] = e4a[i * 64 + lane];
        eb[i] = e4b[i * 64 + lane];
    }
    float4 wv2 = w4[wbase + 1024];
    float4 wv3 = w4[wbase + 1536];

    ogs[t] = o;
    float p = dot4(o, o);
    #pragma unroll
    for (int m = 32; m >= 1; m >>= 1) p += __shfl_xor(p, m, 64);
    if (lane == 0) red[wave] = p;

    {
        ushort4 c0, c1;
        c0.x = f2bf(wv0.x); c0.y = f2bf(wv0.y); c0.z = f2bf(wv0.z); c0.w = f2bf(wv0.w);
        c1.x = f2bf(wv1.x); c1.y = f2bf(wv1.y); c1.z = f2bf(wv1.z); c1.w = f2bf(wv1.w);
        wb4[wbase] = c0;
        wb4[wbase + 512] = c1;
    }
    __syncthreads();

    float og2 = 0.f;
    #pragma unroll
    for (int w = 0; w < 8; ++w) og2 += red[w];
    const float onorm = sqrtf(og2);

    float da = 0.f, na = 0.f, db = 0.f, nb = 0.f;
    #pragma unroll
    for (int i = 0; i < 8; ++i) {
        float4 g = ogs[i * 64 + lane];
        da += dot4(ea[i], g); na += dot4(ea[i], ea[i]);
        db += dot4(eb[i], g); nb += dot4(eb[i], eb[i]);
    }
    #pragma unroll
    for (int m = 32; m >= 1; m >>= 1) {
        da += __shfl_xor(da, m, 64);
        na += __shfl_xor(na, m, 64);
        db += __shfl_xor(db, m, 64);
        nb += __shfl_xor(nb, m, 64);
    }
    const float sima = da / fmaxf(sqrtf(na) * onorm, EPS);
    const float simb = db / fmaxf(sqrtf(nb) * onorm, EPS);

    #pragma unroll
    for (int i = 0; i < 8; ++i) {
        float4 v;
        v.x = ea[i].x * sima + eb[i].x * simb;
        v.y = ea[i].y * sima + eb[i].y * simb;
        v.z = ea[i].z * sima + eb[i].z * simb;
        v.w = ea[i].w * sima + eb[i].w * simb;
        buf[wave][i * 64 + lane] = v;
    }
    {
        ushort4 c2, c3;
        c2.x = f2bf(wv2.x); c2.y = f2bf(wv2.y); c2.z = f2bf(wv2.z); c2.w = f2bf(wv2.w);
        c3.x = f2bf(wv3.x); c3.y = f2bf(wv3.y); c3.z = f2bf(wv3.z); c3.w = f2bf(wv3.w);
        wb4[wbase + 1024] = c2;
        wb4[wbase + 1536] = c3;
    }
    __syncthreads();

    float4 s = buf[0][t];
    #pragma unroll
    for (int w = 1; w < 8; ++w) {
        float4 v = buf[w][t];
        s.x += v.x; s.y += v.y; s.z += v.z; s.w += v.w;
    }
    const float sc = 1.f / (float)S_DIM;
    ushort4 ob;
    ob.x = f2bf(s.x * sc); ob.y = f2bf(s.y * sc);
    ob.z = f2bf(s.z * sc); ob.w = f2bf(s.w * sc);
    ((ushort4*)wrep)[(size_t)b * (H_DIM / 4) + t] = ob;
}

// ---------------- Kernel C: out = wrep @ Wb^T + b  (bf16 MFMA 32x32x16) ----------------
// R7's reg-staged 2-deep pipeline + swizzle + XCD map (all byte-identical),
// with R5's verified K-QUARTER fragment scheme grafted in: each wave computes
// the FULL 64x64 tile (4 acc chains) over its own K=16 slice of each K=64
// window -> every staged fragment is ds_read exactly ONCE (1 read/MFMA vs 2).
// CU LDS instrs per window: 48 -> 32. Cross-wave K-reduce via LDS epilogue
// (R5-verified mapping). This keeps R7's barrier/pipeline structure, so R5's
// failure modes (gll vmcnt(0) drains, 96 KiB dbuf) don't apply.
__global__ __launch_bounds__(256) void gemm_kernel(
    const unsigned short* __restrict__ A, const unsigned short* __restrict__ Wb,
    const float* __restrict__ bias, float* __restrict__ out) {
    const int bid = blockIdx.x;
    const int xcd = bid & 7, j = bid >> 3;
    const int n0 = (xcd * 4 + (j & 3)) * 64;   // 32 n-tiles, 4 per XCD
    const int m0 = (j >> 2) * 64;              // 8 m-tiles

    __shared__ unsigned short As[2][64 * 64];  // 8 KiB each, stride 128 B
    __shared__ unsigned short Bs[2][64 * 64];
    __shared__ float red[4][16][256];          // 64 KiB K-partial exchange

    const int t = threadIdx.x;
    const int lane = t & 63;
    const int kh = t >> 6;                     // wave id == K-quarter

    const int lr = t >> 2, lq = t & 3;   // staging: 4 thr/row, 32 shorts each
    const unsigned short* ap = A  + (size_t)(m0 + lr) * H_DIM + lq * 16;
    const unsigned short* bp = Wb + (size_t)(n0 + lr) * H_DIM + lq * 16;

    // swizzled write offsets (short units): byte = lq*32 (+16) XOR (lr&7)<<4
    const int swz = (lr & 7) << 4;
    const int w0 = lr * 64 + (((lq * 32) ^ swz) >> 1);
    const int w1 = lr * 64 + (((lq * 32 + 16) ^ swz) >> 1);

    f32x16 acc0 = {0.f,0.f,0.f,0.f,0.f,0.f,0.f,0.f,
                   0.f,0.f,0.f,0.f,0.f,0.f,0.f,0.f};
    f32x16 acc1 = acc0, acc2 = acc0, acc3 = acc0;

    // fragment read offset (swizzled): wave kh reads k-slice kh*16..+16 of the
    // K=64 window; rows +32 share the same XOR term ((row+32)&7 == row&7).
    const int row = lane & 31;
    const int hi = lane >> 5;
    const int off0 = row * 64 + (((kh * 32 + hi * 16) ^ ((row & 7) << 4)) >> 1);

    // prologue: T0 -> r-set, T1 -> s-set, write T0 to buf0
    uint4 ra0 = *(const uint4*)(ap);
    uint4 ra1 = *(const uint4*)(ap + 8);
    uint4 rb0 = *(const uint4*)(bp);
    uint4 rb1 = *(const uint4*)(bp + 8);
    uint4 sa0 = *(const uint4*)(ap + 64);
    uint4 sa1 = *(const uint4*)(ap + 72);
    uint4 sb0 = *(const uint4*)(bp + 64);
    uint4 sb1 = *(const uint4*)(bp + 72);
    *(uint4*)&As[0][w0] = ra0;
    *(uint4*)&As[0][w1] = ra1;
    *(uint4*)&Bs[0][w0] = rb0;
    *(uint4*)&Bs[0][w1] = rb1;
    __syncthreads();

    #define MFMA_TILE(BUF)                                                        \
    {                                                                             \
        bf16x8 a0 = *(const bf16x8*)&As[BUF][off0];                               \
        bf16x8 a1 = *(const bf16x8*)&As[BUF][off0 + 2048];                        \
        bf16x8 b0 = *(const bf16x8*)&Bs[BUF][off0];                               \
        bf16x8 b1 = *(const bf16x8*)&Bs[BUF][off0 + 2048];                        \
        acc0 = __builtin_amdgcn_mfma_f32_32x32x16_bf16(a0, b0, acc0, 0, 0, 0);    \
        acc1 = __builtin_amdgcn_mfma_f32_32x32x16_bf16(a0, b1, acc1, 0, 0, 0);    \
        acc2 = __builtin_amdgcn_mfma_f32_32x32x16_bf16(a1, b0, acc2, 0, 0, 0);    \
        acc3 = __builtin_amdgcn_mfma_f32_32x32x16_bf16(a1, b1, acc3, 0, 0, 0);    \
    }

    for (int ki = 0; ki < 32; ki += 2) {
        if (ki + 2 < 32) {  // issue T_{ki+2} into freed r-set
            ra0 = *(const uint4*)(ap + (ki + 2) * 64);
            ra1 = *(const uint4*)(ap + (ki + 2) * 64 + 8);
            rb0 = *(const uint4*)(bp + (ki + 2) * 64);
            rb1 = *(const uint4*)(bp + (ki + 2) * 64 + 8);
        }
        MFMA_TILE(0);
        *(uint4*)&As[1][w0] = sa0;   // T_{ki+1}
        *(uint4*)&As[1][w1] = sa1;
        *(uint4*)&Bs[1][w0] = sb0;
        *(uint4*)&Bs[1][w1] = sb1;
        __syncthreads();
        if (ki + 3 < 32) {  // issue T_{ki+3} into freed s-set
            sa0 = *(const uint4*)(ap + (ki + 3) * 64);
            sa1 = *(const uint4*)(ap + (ki + 3) * 64 + 8);
            sb0 = *(const uint4*)(bp + (ki + 3) * 64);
            sb1 = *(const uint4*)(bp + (ki + 3) * 64 + 8);
        }
        MFMA_TILE(1);
        if (ki + 2 < 32) {
            *(uint4*)&As[0][w0] = ra0;   // T_{ki+2}
            *(uint4*)&As[0][w1] = ra1;
            *(uint4*)&Bs[0][w0] = rb0;
            *(uint4*)&Bs[0][w1] = rb1;
            __syncthreads();
        }
    }
    #undef MFMA_TILE

    // dump this wave's K-partial (R5-verified): slot = chain*4 + r4, 16 B/lane
    #define DUMP(C, ACC)                                                         \
        { _Pragma("unroll")                                                      \
          for (int r4 = 0; r4 < 4; ++r4) {                                       \
              float4 v = {(ACC)[r4*4], (ACC)[r4*4+1], (ACC)[r4*4+2], (ACC)[r4*4+3]}; \
              *(float4*)&red[kh][(C)*4 + r4][lane << 2] = v;                     \
          } }
    DUMP(0, acc0); DUMP(1, acc1); DUMP(2, acc2); DUMP(3, acc3);
    #undef DUMP
    __syncthreads();

    // wave kh merges the 4 K-partials of chain kh (qm=kh>>1, qn=kh&1)
    const int qm = kh >> 1, qn = kh & 1;
    const int col = n0 + qn * 32 + row;
    const float bias0 = bias[col];
    #pragma unroll
    for (int i = 0; i < 4; ++i) {
        const int s = kh * 4 + i;
        float4 v0 = *(float4*)&red[0][s][lane << 2];
        float4 v1 = *(float4*)&red[1][s][lane << 2];
        float4 v2 = *(float4*)&red[2][s][lane << 2];
        float4 v3 = *(float4*)&red[3][s][lane << 2];
        float4 v;
        v.x = v0.x + v1.x + v2.x + v3.x;
        v.y = v0.y + v1.y + v2.y + v3.y;
        v.z = v0.z + v1.z + v2.z + v3.z;
        v.w = v0.w + v1.w + v2.w + v3.w;
        // D mapping (32x32): col = lane&31, row = (r&3) + 8*(r>>2) + 4*hi
        const float vv[4] = {v.x, v.y, v.z, v.w};
        #pragma unroll
        for (int rr = 0; rr < 4; ++rr) {
            const int mr = rr + 8 * i + 4 * hi;
            out[(size_t)(m0 + qm * 32 + mr) * H_DIM + col] = vv[rr] + bias0;
        }
    }
}

extern "C" void kernel_launch(void* const* d_in, const int* in_sizes, int n_in,
                              void* d_out, int out_size, void* d_ws, size_t ws_size,
                              hipStream_t stream) {
    const float* OG   = (const float*)d_in[0];
    const float* E    = (const float*)d_in[1];
    const float* W    = (const float*)d_in[2];
    const float* bias = (const float*)d_in[3];
    float* out = (float*)d_out;

    unsigned short* wrep = (unsigned short*)d_ws;                 // 2 MiB bf16
    unsigned short* Wb   = wrep + (size_t)B_DIM * H_DIM;          // 8 MiB bf16

    fused_kernel<<<B_DIM, 512, 0, stream>>>(OG, E, W, wrep, Wb);
    gemm_kernel<<<256, 256, 0, stream>>>(wrep, Wb, bias, out);
}